// Round 9
// baseline (242.548 us; speedup 1.0000x reference)
//
#include <hip/hip_runtime.h>
#include <math.h>

#define Cn 256
#define Ln 256
#define Bn 2
#define H1 1024
#define NIDX 64
#define NREL 128
#define NCOMBO 16384
#define TROWS 32

typedef __attribute__((ext_vector_type(8))) short bf16x8;
typedef __attribute__((ext_vector_type(4))) float f32x4;
typedef unsigned int u32;

__device__ __forceinline__ float gelu_exact(float x) {
    return 0.5f * x * (1.0f + erff(x * 0.70710678118654752f));
}
__device__ __forceinline__ short f2bf(float f) {
    unsigned u = __float_as_uint(f);
    return (short)((u + 0x7fffu + ((u >> 16) & 1u)) >> 16);   // RNE
}

// ---------------- prep ------------------------------------------------------
// blocks 0..127: fc1 fp32->bf16 in MFMA-fragment order
// blocks 128..255: fc2 likewise; blocks 256..261: mod = silu(c)@ada_w^T+ada_b
// fragment unit u = (c*8 + wave)*16 + nt*8 + ks; hot-load = base + u*512 + lane*8.
__global__ __launch_bounds__(256) void prep_kernel(
    const float* __restrict__ c_BD, const float* __restrict__ ada_w,
    const float* __restrict__ ada_b, const float* __restrict__ fc1_w,
    const float* __restrict__ fc2_w, float* __restrict__ mod,
    short* __restrict__ fc1s, short* __restrict__ fc2s)
{
    const int bid = blockIdx.x;
    const int tid = threadIdx.x;
    if (bid < 128) {
        const int t   = bid * 256 + tid;
        const int row = t >> 5;
        const int cc  = t & 31;
        const int c   = row >> 8, wv = (row >> 5) & 7, nt = (row >> 4) & 1, l15 = row & 15;
        const int ks  = cc >> 2, quad = cc & 3;
        const int lane = quad * 16 + l15;
        const int u   = (c * 8 + wv) * 16 + nt * 8 + ks;
        const float* s = fc1_w + (size_t)row * Cn + cc * 8;
        float4 v0 = *(const float4*)s;
        float4 v1 = *(const float4*)(s + 4);
        bf16x8 o;
        o[0] = f2bf(v0.x); o[1] = f2bf(v0.y); o[2] = f2bf(v0.z); o[3] = f2bf(v0.w);
        o[4] = f2bf(v1.x); o[5] = f2bf(v1.y); o[6] = f2bf(v1.z); o[7] = f2bf(v1.w);
        *(bf16x8*)(fc1s + (size_t)u * 512 + lane * 8) = o;
    } else if (bid < 256) {
        const int t   = (bid - 128) * 256 + tid;
        const int row = t >> 7;
        const int cc  = t & 127;
        const int wv  = (row >> 5) & 7, nt = (row >> 4) & 1, l15 = row & 15;
        const int c   = cc >> 5, ks = (cc >> 2) & 7, quad = cc & 3;
        const int lane = quad * 16 + l15;
        const int u   = (c * 8 + wv) * 16 + nt * 8 + ks;
        const float* s = fc2_w + (size_t)row * H1 + cc * 8;
        float4 v0 = *(const float4*)s;
        float4 v1 = *(const float4*)(s + 4);
        bf16x8 o;
        o[0] = f2bf(v0.x); o[1] = f2bf(v0.y); o[2] = f2bf(v0.z); o[3] = f2bf(v0.w);
        o[4] = f2bf(v1.x); o[5] = f2bf(v1.y); o[6] = f2bf(v1.z); o[7] = f2bf(v1.w);
        *(bf16x8*)(fc2s + (size_t)u * 512 + lane * 8) = o;
    } else {
        int o = (bid - 256) * 256 + tid;
        int b = o / (3 * Cn);
        int j = o - b * (3 * Cn);
        const float* crow = c_BD + b * Cn;
        const float* wrow = ada_w + (size_t)j * Cn;
        float acc = 0.f;
        for (int k = 0; k < Cn; k += 4) {
            float4 cv = *(const float4*)(crow + k);
            float4 wv = *(const float4*)(wrow + k);
            acc += (cv.x / (1.f + expf(-cv.x))) * wv.x;
            acc += (cv.y / (1.f + expf(-cv.y))) * wv.y;
            acc += (cv.z / (1.f + expf(-cv.z))) * wv.z;
            acc += (cv.w / (1.f + expf(-cv.w))) * wv.w;
        }
        mod[o] = acc + ada_b[j];
    }
}

// ---------------- fused table: LN + fc1/gelu + fc2 + gate (R4 champion) ----
// 512 threads (8 waves), 32 combo rows/block, grid=512 -> 2 blocks/CU.
// Weight fragments in pre-swizzled order: every load is base + lane*16,
// a fully-coalesced 1KB VMEM burst.
__global__ __launch_bounds__(512, 4) void table_fused_kernel(
    const float* __restrict__ embed_w, const float* __restrict__ pos_w,
    const float* __restrict__ ln_g, const float* __restrict__ ln_b,
    const short* __restrict__ fc1s, const float* __restrict__ fc1_b,
    const short* __restrict__ fc2s, const float* __restrict__ fc2_b,
    const float* __restrict__ mod, float* __restrict__ table)
{
    __shared__ __align__(16) short h_lds[TROWS][264];   // 16.9 KB
    __shared__ __align__(16) short g_lds[TROWS][264];   // 16.9 KB

    const int tid  = threadIdx.x;
    const int wave = tid >> 6;           // 0..7
    const int lane = tid & 63;
    const int quad = lane >> 4;
    const int l15  = lane & 15;

    const int base = blockIdx.x * TROWS;
    const int b    = base >> 13;
    const int idx  = (base >> 7) & 63;
    const int rel0 = base & 127;

    const float* modb = mod + b * (3 * Cn);
    const float* erow = embed_w + (size_t)idx * Cn;

    // ---- LN phase: wave handles rows wave*4 .. wave*4+3, float4-vectorized
    {
        const int c0 = lane * 4;
        float4 ev = *(const float4*)(erow + c0);
        float4 sc = *(const float4*)(modb + Cn + c0);
        sc.x += 1.f; sc.y += 1.f; sc.z += 1.f; sc.w += 1.f;
        const float4 sh = *(const float4*)(modb + c0);
        const float4 lg = *(const float4*)(ln_g + c0);
        const float4 lb = *(const float4*)(ln_b + c0);
        #pragma unroll
        for (int r4 = 0; r4 < 4; ++r4) {
            const int rr = wave * 4 + r4;
            const float4 p = *(const float4*)(pos_w + (size_t)(rel0 + rr) * Cn + c0);
            float v0 = (ev.x + p.x) * sc.x + sh.x;
            float v1 = (ev.y + p.y) * sc.y + sh.y;
            float v2 = (ev.z + p.z) * sc.z + sh.z;
            float v3 = (ev.w + p.w) * sc.w + sh.w;
            float sum = v0 + v1 + v2 + v3;
            #pragma unroll
            for (int off = 32; off; off >>= 1) sum += __shfl_xor(sum, off, 64);
            const float mu = sum * (1.f / Cn);
            float t0 = v0 - mu, t1 = v1 - mu, t2 = v2 - mu, t3 = v3 - mu;
            float p2 = t0 * t0 + t1 * t1 + t2 * t2 + t3 * t3;
            #pragma unroll
            for (int off = 32; off; off >>= 1) p2 += __shfl_xor(p2, off, 64);
            const float rstd = rsqrtf(p2 * (1.f / Cn) + 1e-5f);
            short4 hq;
            hq.x = f2bf(t0 * rstd * lg.x + lb.x);
            hq.y = f2bf(t1 * rstd * lg.y + lb.y);
            hq.z = f2bf(t2 * rstd * lg.z + lb.z);
            hq.w = f2bf(t3 * rstd * lg.w + lb.w);
            *(short4*)(&h_lds[rr][c0]) = hq;
        }
    }
    __syncthreads();

    f32x4 acc2[2][2];
    #pragma unroll
    for (int mt = 0; mt < 2; ++mt)
        #pragma unroll
        for (int nt = 0; nt < 2; ++nt) acc2[mt][nt] = (f32x4){0.f, 0.f, 0.f, 0.f};

    for (int c = 0; c < 4; ++c) {
        // ---- GEMM1 chunk: z[32 rows][32 cols of this wave's n-slice]
        f32x4 z[2][2];
        #pragma unroll
        for (int mt = 0; mt < 2; ++mt)
            #pragma unroll
            for (int nt = 0; nt < 2; ++nt) z[mt][nt] = (f32x4){0.f, 0.f, 0.f, 0.f};

        {
            const short* w1u = fc1s + (size_t)((c * 8 + wave) * 16) * 512 + lane * 8;
            bf16x8 wf[8][2];
            #pragma unroll
            for (int ks = 0; ks < 8; ++ks)
                #pragma unroll
                for (int nt = 0; nt < 2; ++nt)
                    wf[ks][nt] = *(const bf16x8*)(w1u + (nt * 8 + ks) * 512);
            #pragma unroll
            for (int ks = 0; ks < 8; ++ks) {
                const int k0 = ks * 32 + quad * 8;
                bf16x8 a0 = *(const bf16x8*)(&h_lds[l15][k0]);
                bf16x8 a1 = *(const bf16x8*)(&h_lds[16 + l15][k0]);
                #pragma unroll
                for (int nt = 0; nt < 2; ++nt) {
                    z[0][nt] = __builtin_amdgcn_mfma_f32_16x16x32_bf16(wf[ks][nt], a0, z[0][nt], 0, 0, 0);
                    z[1][nt] = __builtin_amdgcn_mfma_f32_16x16x32_bf16(wf[ks][nt], a1, z[1][nt], 0, 0, 0);
                }
            }
        }
        __syncthreads();   // all waves done reading g_lds of prev c before rewrite

        // gelu + bias, vector store: lane owns 4 consecutive cols (quad*4+r)
        #pragma unroll
        for (int mt = 0; mt < 2; ++mt) {
            #pragma unroll
            for (int nt = 0; nt < 2; ++nt) {
                const int cc = wave * 32 + nt * 16 + quad * 4;
                const float4 b4 = *(const float4*)(fc1_b + c * 256 + cc);
                short4 o;
                o.x = f2bf(gelu_exact(z[mt][nt][0] + b4.x));
                o.y = f2bf(gelu_exact(z[mt][nt][1] + b4.y));
                o.z = f2bf(gelu_exact(z[mt][nt][2] + b4.z));
                o.w = f2bf(gelu_exact(z[mt][nt][3] + b4.w));
                *(short4*)(&g_lds[mt * 16 + l15][cc]) = o;
            }
        }
        __syncthreads();

        // ---- GEMM2 partial-K: acc2 += g_chunk @ w2_chunk^T
        {
            const short* w2u = fc2s + (size_t)((c * 8 + wave) * 16) * 512 + lane * 8;
            bf16x8 wf[8][2];
            #pragma unroll
            for (int ks = 0; ks < 8; ++ks)
                #pragma unroll
                for (int nt = 0; nt < 2; ++nt)
                    wf[ks][nt] = *(const bf16x8*)(w2u + (nt * 8 + ks) * 512);
            #pragma unroll
            for (int ks = 0; ks < 8; ++ks) {
                const int k0 = ks * 32 + quad * 8;
                bf16x8 a0 = *(const bf16x8*)(&g_lds[l15][k0]);
                bf16x8 a1 = *(const bf16x8*)(&g_lds[16 + l15][k0]);
                #pragma unroll
                for (int nt = 0; nt < 2; ++nt) {
                    acc2[0][nt] = __builtin_amdgcn_mfma_f32_16x16x32_bf16(wf[ks][nt], a0, acc2[0][nt], 0, 0, 0);
                    acc2[1][nt] = __builtin_amdgcn_mfma_f32_16x16x32_bf16(wf[ks][nt], a1, acc2[1][nt], 0, 0, 0);
                }
            }
        }
        if (c < 3) __syncthreads();   // g_lds rewritten next iter
    }

    // ---- epilogue: out = s + gate*(acc2 + b2), s recomputed, float4 stores
    #pragma unroll
    for (int mt = 0; mt < 2; ++mt) {
        const int row = mt * 16 + l15;                 // combo row in block
        const float* prow = pos_w + (size_t)(rel0 + row) * Cn;
        #pragma unroll
        for (int nt = 0; nt < 2; ++nt) {
            const int n0 = wave * 32 + nt * 16 + quad * 4;
            const float4 b4 = *(const float4*)(fc2_b + n0);
            const float4 g4 = *(const float4*)(modb + 2 * Cn + n0);
            const float4 sc = *(const float4*)(modb + Cn + n0);
            const float4 sh = *(const float4*)(modb + n0);
            const float4 e4 = *(const float4*)(erow + n0);
            const float4 p4 = *(const float4*)(prow + n0);
            float4 o;
            float s;
            s   = (e4.x + p4.x) * (1.f + sc.x) + sh.x;
            o.x = s + g4.x * (acc2[mt][nt][0] + b4.x);
            s   = (e4.y + p4.y) * (1.f + sc.y) + sh.y;
            o.y = s + g4.y * (acc2[mt][nt][1] + b4.y);
            s   = (e4.z + p4.z) * (1.f + sc.z) + sh.z;
            o.z = s + g4.z * (acc2[mt][nt][2] + b4.z);
            s   = (e4.w + p4.w) * (1.f + sc.w) + sh.w;
            o.w = s + g4.w * (acc2[mt][nt][3] + b4.w);
            *(float4*)(table + (size_t)(base + row) * Cn + n0) = o;
        }
    }
}

// ---------------- gather (R4 champion) + NON-TEMPORAL out stores -----------
// out is write-once/never-read: NT stores keep the 134MB stream from
// evicting table rows out of the 4MiB per-XCD L2s (table has ~8x row reuse).
__global__ __launch_bounds__(256) void gather_kernel(
    const float* __restrict__ x, const float* __restrict__ bins,
    const float* __restrict__ table, float* __restrict__ out)
{
    __shared__ float xs[Ln * 3];
    __shared__ float bins_s[63];
    __shared__ int   idx_s[64];

    const int tid = threadIdx.x;
    const int blk = blockIdx.x;          // (b*256 + i)*4 + q
    const int q   = blk & 3;
    const int bi  = blk >> 2;
    const int b   = bi >> 8;
    const int i   = bi & 255;

    for (int t = tid; t < Ln * 3; t += 256) xs[t] = x[(size_t)b * Ln * 3 + t];
    if (tid < 63) bins_s[tid] = bins[tid];
    __syncthreads();

    if (tid < 64) {
        int j = q * 64 + tid;
        float d0 = xs[3 * i]     - xs[3 * j];
        float d1 = xs[3 * i + 1] - xs[3 * j + 1];
        float d2 = xs[3 * i + 2] - xs[3 * j + 2];
        float d = d0 * d0 + d1 * d1 + d2 * d2;
        int v = 0;
        #pragma unroll
        for (int k = 0; k < 63; ++k) v += (bins_s[k] < d) ? 1 : 0;
        idx_s[tid] = v;
    }
    __syncthreads();

    const int wave = tid >> 6;
    const int lane = tid & 63;
    f32x4* outp = (f32x4*)(out + (size_t)bi * Ln * Cn);
    const f32x4* tab4 = (const f32x4*)table;

    f32x4 v[16];
    #pragma unroll
    for (int jj = 0; jj < 16; ++jj) {
        int jl  = wave * 16 + jj;
        int j   = q * 64 + jl;
        int rel = i - j;
        rel = (rel < -64 ? -64 : (rel > 63 ? 63 : rel)) + 64;
        size_t trow = (size_t)((b * NIDX + idx_s[jl]) * NREL + rel) * (Cn / 4);
        v[jj] = tab4[trow + lane];
    }
    #pragma unroll
    for (int jj = 0; jj < 16; ++jj) {
        int j = q * 64 + wave * 16 + jj;
        __builtin_nontemporal_store(v[jj], outp + (size_t)j * (Cn / 4) + lane);
    }
}

extern "C" void kernel_launch(void* const* d_in, const int* in_sizes, int n_in,
                              void* d_out, int out_size, void* d_ws, size_t ws_size,
                              hipStream_t stream) {
    const float* x_BLD   = (const float*)d_in[0];
    const float* c_BD    = (const float*)d_in[1];
    const float* embed_w = (const float*)d_in[2];
    const float* pos_w   = (const float*)d_in[3];
    const float* bins    = (const float*)d_in[4];
    const float* ada_w   = (const float*)d_in[5];
    const float* ada_b   = (const float*)d_in[6];
    const float* ln_g    = (const float*)d_in[7];
    const float* ln_b    = (const float*)d_in[8];
    const float* fc1_w   = (const float*)d_in[9];
    const float* fc1_b   = (const float*)d_in[10];
    const float* fc2_w   = (const float*)d_in[11];
    const float* fc2_b   = (const float*)d_in[12];
    float* out = (float*)d_out;

    char* ws = (char*)d_ws;
    float* mod   = (float*)ws;                               // 8 KB
    short* fc1s  = (short*)(ws + 8192);                      // 512 KB (fragment order)
    short* fc2s  = (short*)(ws + 8192 + 524288);             // 512 KB (fragment order)
    float* table = (float*)(ws + 8192 + 2 * 524288);         // 16 MB

    prep_kernel<<<262, 256, 0, stream>>>(c_BD, ada_w, ada_b, fc1_w, fc2_w,
                                         mod, fc1s, fc2s);
    table_fused_kernel<<<NCOMBO / TROWS, 512, 0, stream>>>(
        embed_w, pos_w, ln_g, ln_b, fc1s, fc1_b, fc2s, fc2_b, mod, table);
    gather_kernel<<<Bn * Ln * 4, 256, 0, stream>>>(x_BLD, bins, table, out);
}

// Round 10
// 237.809 us; speedup vs baseline: 1.0199x; 1.0199x over previous
//
#include <hip/hip_runtime.h>
#include <math.h>

#define Cn 256
#define Ln 256
#define Bn 2
#define H1 1024
#define NIDX 64
#define NREL 128
#define NCOMBO 16384
#define TROWS 32

typedef __attribute__((ext_vector_type(8))) short bf16x8;
typedef __attribute__((ext_vector_type(4))) float f32x4;
typedef unsigned int u32;

__device__ __forceinline__ float gelu_exact(float x) {
    return 0.5f * x * (1.0f + erff(x * 0.70710678118654752f));
}
__device__ __forceinline__ short f2bf(float f) {
    unsigned u = __float_as_uint(f);
    return (short)((u + 0x7fffu + ((u >> 16) & 1u)) >> 16);   // RNE
}
__device__ __forceinline__ float bf2f(unsigned short s) {
    return __uint_as_float(((unsigned)s) << 16);
}

// ---------------- prep ------------------------------------------------------
// blocks 0..127: fc1 fp32->bf16 in MFMA-fragment order
// blocks 128..255: fc2 likewise; blocks 256..261: mod = silu(c)@ada_w^T+ada_b
// fragment unit u = (c*8 + wave)*16 + nt*8 + ks; hot-load = base + u*512 + lane*8.
__global__ __launch_bounds__(256) void prep_kernel(
    const float* __restrict__ c_BD, const float* __restrict__ ada_w,
    const float* __restrict__ ada_b, const float* __restrict__ fc1_w,
    const float* __restrict__ fc2_w, float* __restrict__ mod,
    short* __restrict__ fc1s, short* __restrict__ fc2s)
{
    const int bid = blockIdx.x;
    const int tid = threadIdx.x;
    if (bid < 128) {
        const int t   = bid * 256 + tid;
        const int row = t >> 5;
        const int cc  = t & 31;
        const int c   = row >> 8, wv = (row >> 5) & 7, nt = (row >> 4) & 1, l15 = row & 15;
        const int ks  = cc >> 2, quad = cc & 3;
        const int lane = quad * 16 + l15;
        const int u   = (c * 8 + wv) * 16 + nt * 8 + ks;
        const float* s = fc1_w + (size_t)row * Cn + cc * 8;
        float4 v0 = *(const float4*)s;
        float4 v1 = *(const float4*)(s + 4);
        bf16x8 o;
        o[0] = f2bf(v0.x); o[1] = f2bf(v0.y); o[2] = f2bf(v0.z); o[3] = f2bf(v0.w);
        o[4] = f2bf(v1.x); o[5] = f2bf(v1.y); o[6] = f2bf(v1.z); o[7] = f2bf(v1.w);
        *(bf16x8*)(fc1s + (size_t)u * 512 + lane * 8) = o;
    } else if (bid < 256) {
        const int t   = (bid - 128) * 256 + tid;
        const int row = t >> 7;
        const int cc  = t & 127;
        const int wv  = (row >> 5) & 7, nt = (row >> 4) & 1, l15 = row & 15;
        const int c   = cc >> 5, ks = (cc >> 2) & 7, quad = cc & 3;
        const int lane = quad * 16 + l15;
        const int u   = (c * 8 + wv) * 16 + nt * 8 + ks;
        const float* s = fc2_w + (size_t)row * H1 + cc * 8;
        float4 v0 = *(const float4*)s;
        float4 v1 = *(const float4*)(s + 4);
        bf16x8 o;
        o[0] = f2bf(v0.x); o[1] = f2bf(v0.y); o[2] = f2bf(v0.z); o[3] = f2bf(v0.w);
        o[4] = f2bf(v1.x); o[5] = f2bf(v1.y); o[6] = f2bf(v1.z); o[7] = f2bf(v1.w);
        *(bf16x8*)(fc2s + (size_t)u * 512 + lane * 8) = o;
    } else {
        int o = (bid - 256) * 256 + tid;
        int b = o / (3 * Cn);
        int j = o - b * (3 * Cn);
        const float* crow = c_BD + b * Cn;
        const float* wrow = ada_w + (size_t)j * Cn;
        float acc = 0.f;
        for (int k = 0; k < Cn; k += 4) {
            float4 cv = *(const float4*)(crow + k);
            float4 wv = *(const float4*)(wrow + k);
            acc += (cv.x / (1.f + expf(-cv.x))) * wv.x;
            acc += (cv.y / (1.f + expf(-cv.y))) * wv.y;
            acc += (cv.z / (1.f + expf(-cv.z))) * wv.z;
            acc += (cv.w / (1.f + expf(-cv.w))) * wv.w;
        }
        mod[o] = acc + ada_b[j];
    }
}

// ---------------- fused table: LN + fc1/gelu + fc2 + gate ------------------
// 512 threads (8 waves), 32 combo rows/block, grid=512 -> 2 blocks/CU.
// Weight fragments pre-swizzled: every load = base + lane*16 (1KB burst).
// OUTPUT NOW bf16: halves table write (8MB) and gather's read stream, and
// the 8MB table doubles its per-XCD L2 residency for gather's ~8x row reuse.
__global__ __launch_bounds__(512, 4) void table_fused_kernel(
    const float* __restrict__ embed_w, const float* __restrict__ pos_w,
    const float* __restrict__ ln_g, const float* __restrict__ ln_b,
    const short* __restrict__ fc1s, const float* __restrict__ fc1_b,
    const short* __restrict__ fc2s, const float* __restrict__ fc2_b,
    const float* __restrict__ mod, short* __restrict__ table)
{
    __shared__ __align__(16) short h_lds[TROWS][264];   // 16.9 KB
    __shared__ __align__(16) short g_lds[TROWS][264];   // 16.9 KB

    const int tid  = threadIdx.x;
    const int wave = tid >> 6;           // 0..7
    const int lane = tid & 63;
    const int quad = lane >> 4;
    const int l15  = lane & 15;

    const int base = blockIdx.x * TROWS;
    const int b    = base >> 13;
    const int idx  = (base >> 7) & 63;
    const int rel0 = base & 127;

    const float* modb = mod + b * (3 * Cn);
    const float* erow = embed_w + (size_t)idx * Cn;

    // ---- LN phase: wave handles rows wave*4 .. wave*4+3, float4-vectorized
    {
        const int c0 = lane * 4;
        float4 ev = *(const float4*)(erow + c0);
        float4 sc = *(const float4*)(modb + Cn + c0);
        sc.x += 1.f; sc.y += 1.f; sc.z += 1.f; sc.w += 1.f;
        const float4 sh = *(const float4*)(modb + c0);
        const float4 lg = *(const float4*)(ln_g + c0);
        const float4 lb = *(const float4*)(ln_b + c0);
        #pragma unroll
        for (int r4 = 0; r4 < 4; ++r4) {
            const int rr = wave * 4 + r4;
            const float4 p = *(const float4*)(pos_w + (size_t)(rel0 + rr) * Cn + c0);
            float v0 = (ev.x + p.x) * sc.x + sh.x;
            float v1 = (ev.y + p.y) * sc.y + sh.y;
            float v2 = (ev.z + p.z) * sc.z + sh.z;
            float v3 = (ev.w + p.w) * sc.w + sh.w;
            float sum = v0 + v1 + v2 + v3;
            #pragma unroll
            for (int off = 32; off; off >>= 1) sum += __shfl_xor(sum, off, 64);
            const float mu = sum * (1.f / Cn);
            float t0 = v0 - mu, t1 = v1 - mu, t2 = v2 - mu, t3 = v3 - mu;
            float p2 = t0 * t0 + t1 * t1 + t2 * t2 + t3 * t3;
            #pragma unroll
            for (int off = 32; off; off >>= 1) p2 += __shfl_xor(p2, off, 64);
            const float rstd = rsqrtf(p2 * (1.f / Cn) + 1e-5f);
            short4 hq;
            hq.x = f2bf(t0 * rstd * lg.x + lb.x);
            hq.y = f2bf(t1 * rstd * lg.y + lb.y);
            hq.z = f2bf(t2 * rstd * lg.z + lb.z);
            hq.w = f2bf(t3 * rstd * lg.w + lb.w);
            *(short4*)(&h_lds[rr][c0]) = hq;
        }
    }
    __syncthreads();

    f32x4 acc2[2][2];
    #pragma unroll
    for (int mt = 0; mt < 2; ++mt)
        #pragma unroll
        for (int nt = 0; nt < 2; ++nt) acc2[mt][nt] = (f32x4){0.f, 0.f, 0.f, 0.f};

    for (int c = 0; c < 4; ++c) {
        // ---- GEMM1 chunk: z[32 rows][32 cols of this wave's n-slice]
        f32x4 z[2][2];
        #pragma unroll
        for (int mt = 0; mt < 2; ++mt)
            #pragma unroll
            for (int nt = 0; nt < 2; ++nt) z[mt][nt] = (f32x4){0.f, 0.f, 0.f, 0.f};

        {
            const short* w1u = fc1s + (size_t)((c * 8 + wave) * 16) * 512 + lane * 8;
            bf16x8 wf[8][2];
            #pragma unroll
            for (int ks = 0; ks < 8; ++ks)
                #pragma unroll
                for (int nt = 0; nt < 2; ++nt)
                    wf[ks][nt] = *(const bf16x8*)(w1u + (nt * 8 + ks) * 512);
            #pragma unroll
            for (int ks = 0; ks < 8; ++ks) {
                const int k0 = ks * 32 + quad * 8;
                bf16x8 a0 = *(const bf16x8*)(&h_lds[l15][k0]);
                bf16x8 a1 = *(const bf16x8*)(&h_lds[16 + l15][k0]);
                #pragma unroll
                for (int nt = 0; nt < 2; ++nt) {
                    z[0][nt] = __builtin_amdgcn_mfma_f32_16x16x32_bf16(wf[ks][nt], a0, z[0][nt], 0, 0, 0);
                    z[1][nt] = __builtin_amdgcn_mfma_f32_16x16x32_bf16(wf[ks][nt], a1, z[1][nt], 0, 0, 0);
                }
            }
        }
        __syncthreads();   // all waves done reading g_lds of prev c before rewrite

        // gelu + bias, vector store: lane owns 4 consecutive cols (quad*4+r)
        #pragma unroll
        for (int mt = 0; mt < 2; ++mt) {
            #pragma unroll
            for (int nt = 0; nt < 2; ++nt) {
                const int cc = wave * 32 + nt * 16 + quad * 4;
                const float4 b4 = *(const float4*)(fc1_b + c * 256 + cc);
                short4 o;
                o.x = f2bf(gelu_exact(z[mt][nt][0] + b4.x));
                o.y = f2bf(gelu_exact(z[mt][nt][1] + b4.y));
                o.z = f2bf(gelu_exact(z[mt][nt][2] + b4.z));
                o.w = f2bf(gelu_exact(z[mt][nt][3] + b4.w));
                *(short4*)(&g_lds[mt * 16 + l15][cc]) = o;
            }
        }
        __syncthreads();

        // ---- GEMM2 partial-K: acc2 += g_chunk @ w2_chunk^T
        {
            const short* w2u = fc2s + (size_t)((c * 8 + wave) * 16) * 512 + lane * 8;
            bf16x8 wf[8][2];
            #pragma unroll
            for (int ks = 0; ks < 8; ++ks)
                #pragma unroll
                for (int nt = 0; nt < 2; ++nt)
                    wf[ks][nt] = *(const bf16x8*)(w2u + (nt * 8 + ks) * 512);
            #pragma unroll
            for (int ks = 0; ks < 8; ++ks) {
                const int k0 = ks * 32 + quad * 8;
                bf16x8 a0 = *(const bf16x8*)(&g_lds[l15][k0]);
                bf16x8 a1 = *(const bf16x8*)(&g_lds[16 + l15][k0]);
                #pragma unroll
                for (int nt = 0; nt < 2; ++nt) {
                    acc2[0][nt] = __builtin_amdgcn_mfma_f32_16x16x32_bf16(wf[ks][nt], a0, acc2[0][nt], 0, 0, 0);
                    acc2[1][nt] = __builtin_amdgcn_mfma_f32_16x16x32_bf16(wf[ks][nt], a1, acc2[1][nt], 0, 0, 0);
                }
            }
        }
        if (c < 3) __syncthreads();   // g_lds rewritten next iter
    }

    // ---- epilogue: out = s + gate*(acc2 + b2), s recomputed, bf16 store
    #pragma unroll
    for (int mt = 0; mt < 2; ++mt) {
        const int row = mt * 16 + l15;                 // combo row in block
        const float* prow = pos_w + (size_t)(rel0 + row) * Cn;
        #pragma unroll
        for (int nt = 0; nt < 2; ++nt) {
            const int n0 = wave * 32 + nt * 16 + quad * 4;
            const float4 b4 = *(const float4*)(fc2_b + n0);
            const float4 g4 = *(const float4*)(modb + 2 * Cn + n0);
            const float4 sc = *(const float4*)(modb + Cn + n0);
            const float4 sh = *(const float4*)(modb + n0);
            const float4 e4 = *(const float4*)(erow + n0);
            const float4 p4 = *(const float4*)(prow + n0);
            float s;
            short4 o;
            s   = (e4.x + p4.x) * (1.f + sc.x) + sh.x;
            o.x = f2bf(s + g4.x * (acc2[mt][nt][0] + b4.x));
            s   = (e4.y + p4.y) * (1.f + sc.y) + sh.y;
            o.y = f2bf(s + g4.y * (acc2[mt][nt][1] + b4.y));
            s   = (e4.z + p4.z) * (1.f + sc.z) + sh.z;
            o.z = f2bf(s + g4.z * (acc2[mt][nt][2] + b4.z));
            s   = (e4.w + p4.w) * (1.f + sc.w) + sh.w;
            o.w = f2bf(s + g4.w * (acc2[mt][nt][3] + b4.w));
            *(short4*)(table + (size_t)(base + row) * Cn + n0) = o;
        }
    }
}

// ---------------- gather: bf16 table read -> f32 NT store ------------------
// lane reads ushort4 (8B) of its 4 channels: 512B coalesced burst per row.
// Up-convert bf16->f32 is a shift; out stream stays NT (write-once).
__global__ __launch_bounds__(256) void gather_kernel(
    const float* __restrict__ x, const float* __restrict__ bins,
    const short* __restrict__ table, float* __restrict__ out)
{
    __shared__ float xs[Ln * 3];
    __shared__ float bins_s[63];
    __shared__ int   idx_s[64];

    const int tid = threadIdx.x;
    const int blk = blockIdx.x;          // (b*256 + i)*4 + q
    const int q   = blk & 3;
    const int bi  = blk >> 2;
    const int b   = bi >> 8;
    const int i   = bi & 255;

    for (int t = tid; t < Ln * 3; t += 256) xs[t] = x[(size_t)b * Ln * 3 + t];
    if (tid < 63) bins_s[tid] = bins[tid];
    __syncthreads();

    if (tid < 64) {
        int j = q * 64 + tid;
        float d0 = xs[3 * i]     - xs[3 * j];
        float d1 = xs[3 * i + 1] - xs[3 * j + 1];
        float d2 = xs[3 * i + 2] - xs[3 * j + 2];
        float d = d0 * d0 + d1 * d1 + d2 * d2;
        int v = 0;
        #pragma unroll
        for (int k = 0; k < 63; ++k) v += (bins_s[k] < d) ? 1 : 0;
        idx_s[tid] = v;
    }
    __syncthreads();

    const int wave = tid >> 6;
    const int lane = tid & 63;
    f32x4* outp = (f32x4*)(out + (size_t)bi * Ln * Cn);
    const ushort4* tab4 = (const ushort4*)table;   // 4 channels / lane

    ushort4 v[16];
    #pragma unroll
    for (int jj = 0; jj < 16; ++jj) {
        int jl  = wave * 16 + jj;
        int j   = q * 64 + jl;
        int rel = i - j;
        rel = (rel < -64 ? -64 : (rel > 63 ? 63 : rel)) + 64;
        size_t trow = (size_t)((b * NIDX + idx_s[jl]) * NREL + rel) * (Cn / 4);
        v[jj] = tab4[trow + lane];
    }
    #pragma unroll
    for (int jj = 0; jj < 16; ++jj) {
        int j = q * 64 + wave * 16 + jj;
        f32x4 o;
        o[0] = bf2f(v[jj].x);
        o[1] = bf2f(v[jj].y);
        o[2] = bf2f(v[jj].z);
        o[3] = bf2f(v[jj].w);
        __builtin_nontemporal_store(o, outp + (size_t)j * (Cn / 4) + lane);
    }
}

extern "C" void kernel_launch(void* const* d_in, const int* in_sizes, int n_in,
                              void* d_out, int out_size, void* d_ws, size_t ws_size,
                              hipStream_t stream) {
    const float* x_BLD   = (const float*)d_in[0];
    const float* c_BD    = (const float*)d_in[1];
    const float* embed_w = (const float*)d_in[2];
    const float* pos_w   = (const float*)d_in[3];
    const float* bins    = (const float*)d_in[4];
    const float* ada_w   = (const float*)d_in[5];
    const float* ada_b   = (const float*)d_in[6];
    const float* ln_g    = (const float*)d_in[7];
    const float* ln_b    = (const float*)d_in[8];
    const float* fc1_w   = (const float*)d_in[9];
    const float* fc1_b   = (const float*)d_in[10];
    const float* fc2_w   = (const float*)d_in[11];
    const float* fc2_b   = (const float*)d_in[12];
    float* out = (float*)d_out;

    char* ws = (char*)d_ws;
    float* mod   = (float*)ws;                               // 8 KB
    short* fc1s  = (short*)(ws + 8192);                      // 512 KB (fragment order)
    short* fc2s  = (short*)(ws + 8192 + 524288);             // 512 KB (fragment order)
    short* table = (short*)(ws + 8192 + 2 * 524288);         // 8 MB (bf16)

    prep_kernel<<<262, 256, 0, stream>>>(c_BD, ada_w, ada_b, fc1_w, fc2_w,
                                         mod, fc1s, fc2s);
    table_fused_kernel<<<NCOMBO / TROWS, 512, 0, stream>>>(
        embed_w, pos_w, ln_g, ln_b, fc1s, fc1_b, fc2s, fc2_b, mod, table);
    gather_kernel<<<Bn * Ln * 4, 256, 0, stream>>>(x_BLD, bins, table, out);
}